// Round 17
// baseline (69.867 us; speedup 1.0000x reference)
//
#include <hip/hip_runtime.h>
#include <stdint.h>

// x (8,3,40,128,128) f32, W (16,3,3,3,3) f32, b (16) f32.
// conv3d VALID -> softmax(C=16) -> 4x4x4 truncating maxpool -> (8,16,9,31,31).
//
// R17: 32x32x16 MFMA with DUPLICATED weight rows -> fully in-lane softmax.
//  R14-16 failed only on the lane^32 denominator exchange (permlane semantics
//  unverifiable here; conv part was provably right from the 0.14 structured
//  error). Fix: A rows 16-31 replicate oc with complementary assignment
//  oc(row>=16) = (row-16)^4, so each lane's 16 C-regs hold ALL 16 channels
//  (q=0 lanes: rows {0-3,8-11,16-19,24-27} = oc {0-3,8-11,4-7,12-15}).
//  Softmax = 16 exp2 + in-lane add tree + rcp. No cross-lane at all.
//  MFMA cost unchanged (rows 16-31 were zeros before).

typedef float f16v __attribute__((ext_vector_type(16)));
typedef short s8v  __attribute__((ext_vector_type(8)));
typedef unsigned int u2v __attribute__((ext_vector_type(2), aligned(4)));

#define LOG2E 1.44269504088896340736f

__device__ __host__ inline uint32_t bf16rnd(float x) {
    uint32_t u = __float_as_uint(x);
    return (u + 0x7FFFu + ((u >> 16) & 1u)) >> 16;
}

// A table: 7 MFMAs x 64 lanes x 4 dwords. A[row = lane&31][k=(q,r,half)],
// q = lane>>5; plane p = 4m + 2q + (r>>1):
//   r even: {w[kw0] | w[kw1]<<16};  r odd: {0 | w[kw2]<<16};  p>=27 -> 0.
// Row->channel: oc = row (row<16), oc = (row-16)^4 (row>=16)  [duplication].
__global__ void build_afrag(const float* __restrict__ W, uint32_t* __restrict__ wd) {
    int idx = blockIdx.x * 256 + threadIdx.x;   // 7*64*4 = 1792 entries
    if (idx < 1792) {
        int r = idx & 3, l = (idx >> 2) & 63, m = idx >> 8;
        int row = l & 31, q = l >> 5;
        int oc = (row < 16) ? row : ((row - 16) ^ 4);
        int p = 4 * m + 2 * q + (r >> 1);
        uint32_t v = 0;
        if (p < 27) {
            int ci = p / 9, kd = (p / 3) % 3, kh = p % 3;
            const float* wb = W + (((oc * 3 + ci) * 3 + kd) * 3 + kh) * 3;
            if (r & 1) v = bf16rnd(wb[2] * LOG2E) << 16;
            else       v = bf16rnd(wb[0] * LOG2E) | (bf16rnd(wb[1] * LOG2E) << 16);
        }
        wd[idx] = v;
    }
}

template<int CTRL>
__device__ inline float dppf(float v) {
    return __int_as_float(__builtin_amdgcn_update_dpp(
        0, __float_as_int(v), CTRL, 0xF, 0xF, true));
}

__global__ __launch_bounds__(256, 4)
void conv_softmax_pool(const float* __restrict__ x,
                       const float* __restrict__ bias,
                       const uint32_t* __restrict__ wd,
                       float* __restrict__ out) {
    const int bid = blockIdx.x;
    const int wt  = bid & 1;            // w-tile: wo 0..15 / 16..30
    const int ho  = (bid >> 1) % 31;
    const int dpo = (bid / 62) % 9;
    const int b   = bid / 558;          // 558 = 2*31*9

    const int w0 = wt * 64;
    const int h0 = ho * 4;
    const int d0 = dpo * 4;

    __shared__ uint32_t xs[108 * 66];   // 28512 B; row = (ci*6+d)*6+h
    __shared__ float red[2][16][17];    // dd-pair partial pool, 2176 B

    const int tid = threadIdx.x;

    // ---- stage: entry[row][w] = {bf16 x[w] | bf16 x[w+1]<<16} (R12 proven) ----
    const size_t xbase = (size_t)b * (3ull * 40 * 128 * 128);
    {
        int pw  = tid % 33;
        int row = tid / 33;
        #pragma unroll 1
        for (int it = 0; it < 14; ++it) {
            if (row < 108) {
                int h   = row % 6;
                int d   = (row / 6) % 6;
                int ci  = row / 36;
                int gw = w0 + 2 * pw;
                if (gw > 124) gw = 124;  // extras feed discarded cols only
                const float* xp = x + xbase + ((size_t)ci * 40 + (d0 + d)) * 16384
                                            + (size_t)(h0 + h) * 128 + gw;
                float2 v01 = *(const float2*)xp;
                float  v2  = xp[2];
                uint2 pr;
                asm("v_cvt_pk_bf16_f32 %0, %1, %2" : "=v"(pr.x) : "v"(v01.x), "v"(v01.y));
                asm("v_cvt_pk_bf16_f32 %0, %1, %2" : "=v"(pr.y) : "v"(v01.y), "v"(v2));
                *(uint2*)&xs[row * 66 + 2 * pw] = pr;
            }
            pw += 25; row += 7;
            if (pw >= 33) { pw -= 33; row += 1; }
        }
    }

    const int lane = tid & 63;
    const int wv   = tid >> 6;
    const int wdp  = wv >> 1;           // dd-pair: dd in {2wdp, 2wdp+1}
    const int wp   = wv & 1;            // position half: w = w0 + 32wp + p5
    const int p5   = lane & 31;         // B col = position
    const int q    = lane >> 5;         // k-group / row-half select

    // weight A-fragments (7 MFMAs)
    s8v aW[7];
    {
        const uint4* wsp = (const uint4*)wd;
        #pragma unroll
        for (int m = 0; m < 7; ++m)
            aW[m] = __builtin_bit_cast(s8v, wsp[m * 64 + lane]);
    }
    // per-lane plane dword-offsets (2 planes per MFMA; clamp -> A entries 0)
    uint32_t pA[7], pB[7];
    #pragma unroll
    for (int m = 0; m < 7; ++m) {
        int pa = 4 * m + 2 * q;     if (pa > 26) pa = 26;
        int pb = 4 * m + 2 * q + 1; if (pb > 26) pb = 26;
        pA[m] = (uint32_t)((pa / 9) * 36 + ((pa / 3) % 3) * 6 + pa % 3) * 66u;
        pB[m] = (uint32_t)((pb / 9) * 36 + ((pb / 3) % 3) * 6 + pb % 3) * 66u;
    }
    const uint32_t base0 = (uint32_t)(32 * wp + p5);

    // bias quads for this lane's reg groups j=0..3:
    // oc(reg) = 8*(j&1) + 4*((j>>1)^q) + (reg&3)
    const float4* bp = (const float4*)bias;
    float4 bj0 = bp[q];         // regs 0-3
    float4 bj1 = bp[2 + q];     // regs 4-7
    float4 bj2 = bp[1 - q];     // regs 8-11
    float4 bj3 = bp[3 - q];     // regs 12-15

    __syncthreads();

    float pool0 = 0.f, pool1 = 0.f, pool2 = 0.f, pool3 = 0.f;
    float pool4 = 0.f, pool5 = 0.f, pool6 = 0.f, pool7 = 0.f;

    #pragma unroll 1
    for (int di = 0; di < 2; ++di) {
        const int dd = 2 * wdp + di;
        #pragma unroll 1
        for (int hh = 0; hh < 4; ++hh) {
            const uint32_t tb = base0 + (uint32_t)((dd * 6 + hh) * 66);
            f16v acc;
            acc[0]  = bj0.x * LOG2E; acc[1]  = bj0.y * LOG2E;
            acc[2]  = bj0.z * LOG2E; acc[3]  = bj0.w * LOG2E;
            acc[4]  = bj1.x * LOG2E; acc[5]  = bj1.y * LOG2E;
            acc[6]  = bj1.z * LOG2E; acc[7]  = bj1.w * LOG2E;
            acc[8]  = bj2.x * LOG2E; acc[9]  = bj2.y * LOG2E;
            acc[10] = bj2.z * LOG2E; acc[11] = bj2.w * LOG2E;
            acc[12] = bj3.x * LOG2E; acc[13] = bj3.y * LOG2E;
            acc[14] = bj3.z * LOG2E; acc[15] = bj3.w * LOG2E;

            #pragma unroll
            for (int m = 0; m < 7; ++m) {
                u2v ra = *(const u2v*)&xs[tb + pA[m]];   // 32-consecutive window
                u2v rb = *(const u2v*)&xs[tb + pB[m]];   // -> conflict-free
                union { uint32_t u[4]; s8v s; } B;
                B.u[0] = ra.x; B.u[1] = ra.y; B.u[2] = rb.x; B.u[3] = rb.y;
                acc = __builtin_amdgcn_mfma_f32_32x32x16_bf16(aW[m], B.s, acc, 0, 0, 0);
            }

            // fully in-lane softmax over 16 oc (all channels present in regs)
            float e0  = __builtin_amdgcn_exp2f(acc[0]);
            float e1  = __builtin_amdgcn_exp2f(acc[1]);
            float e2  = __builtin_amdgcn_exp2f(acc[2]);
            float e3  = __builtin_amdgcn_exp2f(acc[3]);
            float e4  = __builtin_amdgcn_exp2f(acc[4]);
            float e5  = __builtin_amdgcn_exp2f(acc[5]);
            float e6  = __builtin_amdgcn_exp2f(acc[6]);
            float e7  = __builtin_amdgcn_exp2f(acc[7]);
            float e8  = __builtin_amdgcn_exp2f(acc[8]);
            float e9  = __builtin_amdgcn_exp2f(acc[9]);
            float e10 = __builtin_amdgcn_exp2f(acc[10]);
            float e11 = __builtin_amdgcn_exp2f(acc[11]);
            float e12 = __builtin_amdgcn_exp2f(acc[12]);
            float e13 = __builtin_amdgcn_exp2f(acc[13]);
            float e14 = __builtin_amdgcn_exp2f(acc[14]);
            float e15 = __builtin_amdgcn_exp2f(acc[15]);
            float s = (((e0 + e1) + (e2 + e3)) + ((e4 + e5) + (e6 + e7)))
                    + (((e8 + e9) + (e10 + e11)) + ((e12 + e13) + (e14 + e15)));
            float inv = __builtin_amdgcn_rcpf(s);
            pool0 = fmaxf(pool0, e0 * inv);
            pool1 = fmaxf(pool1, e1 * inv);
            pool2 = fmaxf(pool2, e2 * inv);
            pool3 = fmaxf(pool3, e3 * inv);
            pool4 = fmaxf(pool4, e4 * inv);
            pool5 = fmaxf(pool5, e5 * inv);
            pool6 = fmaxf(pool6, e6 * inv);
            pool7 = fmaxf(pool7, e7 * inv);
        }
    }

    // w-pool over quads (positions 4k..4k+3 within lane&31)
    #define QPOOL(P) P = fmaxf(P, dppf<0xB1>(P)); P = fmaxf(P, dppf<0x4E>(P))
    QPOOL(pool0); QPOOL(pool1); QPOOL(pool2); QPOOL(pool3);
    QPOOL(pool4); QPOOL(pool5); QPOOL(pool6); QPOOL(pool7);
    #undef QPOOL

    // writer lanes: regs 0-7 cover oc {0-3,8-11} (q=0) / {4-7,12-15} (q=1)
    if ((p5 & 3) == 0) {
        int cell = 8 * wp + (p5 >> 2);   // 0..15
        float pr[8] = {pool0, pool1, pool2, pool3, pool4, pool5, pool6, pool7};
        #pragma unroll
        for (int r = 0; r < 8; ++r)
            red[wdp][cell][(r & 3) + 8 * (r >> 2) + 4 * q] = pr[r];
    }
    __syncthreads();

    // merge dd-pairs, write coalesced (cell ascending = w ascending)
    {
        int cell = tid & 15;
        int oc   = tid >> 4;
        if (tid < 256) {
            float v = fmaxf(red[0][cell][oc], red[1][cell][oc]);
            int wo = wt * 16 + cell;
            if (wo < 31)
                out[(((size_t)b * 16 + oc) * 9 + dpo) * 961
                    + (size_t)ho * 31 + wo] = v;
        }
    }
}

extern "C" void kernel_launch(void* const* d_in, const int* in_sizes, int n_in,
                              void* d_out, int out_size, void* d_ws, size_t ws_size,
                              hipStream_t stream) {
    const float* x  = (const float*)d_in[0];
    const float* W  = (const float*)d_in[1];
    const float* bb = (const float*)d_in[2];
    float* out = (float*)d_out;

    hipLaunchKernelGGL(build_afrag, dim3(7), dim3(256), 0, stream,
                       W, (uint32_t*)d_ws);

    const int blocks = 8 * 9 * 31 * 2;  // 4464
    hipLaunchKernelGGL(conv_softmax_pool, dim3(blocks), dim3(256), 0, stream,
                       x, bb, (const uint32_t*)d_ws, out);
}